// Round 1
// baseline (81.059 us; speedup 1.0000x reference)
//
#include <hip/hip_runtime.h>

// Problem constants (fixed by reference setup_inputs):
//   x: (8,3,512,512) fp32  -- ONLY used for shape, never read
//   coords: (8,48,3) fp32  -- (row,col,_) per point; 2 groups x 24 clicks
//   out: (8,2,512,512) fp32
#define HH 512
#define WW 512
#define PP 24      // clicks per group
#define NPT 48     // points per batch (2 groups)

__global__ __launch_bounds__(256) void DistMaps_37434934952233_kernel(
    const float* __restrict__ coords, float* __restrict__ out)
{
    // 256 blocks per (b,g) map (2 rows each), 16 maps -> 4096 blocks
    const int blk  = blockIdx.x;
    const int map  = blk >> 8;           // b*2 + g
    const int row0 = (blk & 255) << 1;   // 2 rows per block
    const int b    = map >> 1;
    const int g    = map & 1;

    constexpr float INV_SCALE = 1.0f / 5.0f;  // 1/(NORM_RADIUS*SPATIAL_SCALE)

    __shared__ float spr[PP];
    __shared__ float spc[PP];

    const int t = threadIdx.x;
    if (t < PP) {
        const float* cp = coords + (size_t)(b * NPT + g * PP + t) * 3;
        float pr = cp[0];
        float pc = cp[1];
        // invalid iff max(pr,pc) < 0 (checked BEFORE scaling, per reference).
        // Fold invalid -> far-away point: d2 ~ 2e10, tanh saturates to 1.0f
        // exactly, same as reference's INVALID_FILL=1e6 path.
        bool invalid = fmaxf(pr, pc) < 0.0f;
        spr[t] = invalid ? 1.0e5f : pr * INV_SCALE;
        spc[t] = invalid ? 1.0e5f : pc * INV_SCALE;
    }
    __syncthreads();

    const int r  = row0 + (t >> 7);       // row within map
    const int c0 = (t & 127) << 2;        // 4 consecutive cols per thread

    const float rs  = (float)r  * INV_SCALE;
    const float cs0 = (float)c0 * INV_SCALE;
    const float cs1 = cs0 + INV_SCALE;
    const float cs2 = cs0 + 2.0f * INV_SCALE;
    const float cs3 = cs0 + 3.0f * INV_SCALE;

    float m0 = 1e30f, m1 = 1e30f, m2 = 1e30f, m3 = 1e30f;

    #pragma unroll
    for (int p = 0; p < PP; ++p) {
        const float pr = spr[p];
        const float pc = spc[p];
        const float dr  = rs - pr;
        const float dr2 = dr * dr;
        float d;
        d = cs0 - pc; m0 = fminf(m0, fmaf(d, d, dr2));
        d = cs1 - pc; m1 = fminf(m1, fmaf(d, d, dr2));
        d = cs2 - pc; m2 = fminf(m2, fmaf(d, d, dr2));
        d = cs3 - pc; m3 = fminf(m3, fmaf(d, d, dr2));
    }

    float4 o;
    o.x = tanhf(2.0f * sqrtf(m0));
    o.y = tanhf(2.0f * sqrtf(m1));
    o.z = tanhf(2.0f * sqrtf(m2));
    o.w = tanhf(2.0f * sqrtf(m3));

    const size_t idx = ((size_t)map * HH + r) * WW + c0;
    *reinterpret_cast<float4*>(out + idx) = o;
}

extern "C" void kernel_launch(void* const* d_in, const int* in_sizes, int n_in,
                              void* d_out, int out_size, void* d_ws, size_t ws_size,
                              hipStream_t stream) {
    (void)in_sizes; (void)n_in; (void)d_ws; (void)ws_size; (void)out_size;
    const float* coords = (const float*)d_in[1];   // d_in[0] = x (unused)
    float* out = (float*)d_out;
    // 16 maps * 256 blocks/map = 4096 blocks; 256 thr * 4 px = 1024 px = 2 rows
    DistMaps_37434934952233_kernel<<<4096, 256, 0, stream>>>(coords, out);
}

// Round 2
// 73.343 us; speedup vs baseline: 1.1052x; 1.1052x over previous
//
#include <hip/hip_runtime.h>

// DistMaps: out[b,g,r,c] = tanh(2*sqrt(min_p ((r-pr)/5)^2 + ((c-pc)/5)^2))
//   x: (8,3,512,512) fp32  -- shape only, never read
//   coords: (8,48,3) fp32  -- 2 groups x 24 clicks; invalid iff max(r,c)<0
//   out: (8,2,512,512) fp32
#define HH 512
#define WW 512
#define PP 24
#define NPT 48
#define TH 16   // tile rows
#define TW 64   // tile cols
// Cull radius (pixels): beyond 16 px, tanh(2*d/5) >= tanh(6.4) = 1-5.5e-6 -> 1.0f
#define RCUT2 256.0f

__device__ __forceinline__ float tanh2sqrt(float m) {
    // tanh(2*sqrt(m)) = (1-e)/(1+e), e = exp(-4*sqrt(m)); exact 1.0 on underflow
    float s = __builtin_amdgcn_sqrtf(m);
    float e = __expf(-4.0f * s);
    return __fdividef(1.0f - e, 1.0f + e);
}

__global__ __launch_bounds__(256) void DistMaps_37434934952233_kernel(
    const float* __restrict__ coords, float* __restrict__ out)
{
    const int blk  = blockIdx.x;
    const int map  = blk >> 8;         // b*2+g, 16 maps
    const int tile = blk & 255;        // 256 tiles/map: 32 tile-rows x 8 tile-cols
    const int r0   = (tile >> 3) << 4; // *TH
    const int c0   = (tile & 7) << 6;  // *TW
    const int b    = map >> 1;
    const int g    = map & 1;

    constexpr float INV_SCALE = 1.0f / 5.0f;

    __shared__ float npr[PP];
    __shared__ float npc[PP];
    __shared__ int   nnear;

    const int t = threadIdx.x;
    if (t == 0) nnear = 0;
    __syncthreads();

    if (t < PP) {
        const float* cp = coords + (size_t)(b * NPT + g * PP + t) * 3;
        const float pr = cp[0];
        const float pc = cp[1];
        const bool valid = fmaxf(pr, pc) >= 0.0f;   // reference: invalid iff max<0
        // min distance^2 from point to this tile's pixel rectangle
        const float dr = fmaxf(0.0f, fmaxf((float)r0 - pr, pr - (float)(r0 + TH - 1)));
        const float dc = fmaxf(0.0f, fmaxf((float)c0 - pc, pc - (float)(c0 + TW - 1)));
        if (valid && (dr * dr + dc * dc) <= RCUT2) {
            const int i = atomicAdd(&nnear, 1);
            npr[i] = pr * INV_SCALE;
            npc[i] = pc * INV_SCALE;
        }
    }
    __syncthreads();

    const int r  = r0 + (t >> 4);
    const int cc = c0 + ((t & 15) << 2);   // 4 consecutive cols per thread
    const int n  = nnear;

    float4 o;
    if (n == 0) {
        o.x = 1.0f; o.y = 1.0f; o.z = 1.0f; o.w = 1.0f;
    } else {
        const float rs  = (float)r  * INV_SCALE;
        const float cs0 = (float)cc * INV_SCALE;
        const float cs1 = cs0 + INV_SCALE;
        const float cs2 = cs0 + 2.0f * INV_SCALE;
        const float cs3 = cs0 + 3.0f * INV_SCALE;

        float m0 = 1e30f, m1 = 1e30f, m2 = 1e30f, m3 = 1e30f;
        for (int p = 0; p < n; ++p) {
            const float pr = npr[p];
            const float pc = npc[p];
            const float dr  = rs - pr;
            const float dr2 = dr * dr;
            float d;
            d = cs0 - pc; m0 = fminf(m0, fmaf(d, d, dr2));
            d = cs1 - pc; m1 = fminf(m1, fmaf(d, d, dr2));
            d = cs2 - pc; m2 = fminf(m2, fmaf(d, d, dr2));
            d = cs3 - pc; m3 = fminf(m3, fmaf(d, d, dr2));
        }
        o.x = tanh2sqrt(m0);
        o.y = tanh2sqrt(m1);
        o.z = tanh2sqrt(m2);
        o.w = tanh2sqrt(m3);
    }

    const size_t idx = ((size_t)map * HH + r) * WW + cc;
    *reinterpret_cast<float4*>(out + idx) = o;
}

extern "C" void kernel_launch(void* const* d_in, const int* in_sizes, int n_in,
                              void* d_out, int out_size, void* d_ws, size_t ws_size,
                              hipStream_t stream) {
    (void)in_sizes; (void)n_in; (void)d_ws; (void)ws_size; (void)out_size;
    const float* coords = (const float*)d_in[1];   // d_in[0] = x (unused)
    float* out = (float*)d_out;
    DistMaps_37434934952233_kernel<<<16 * 256, 256, 0, stream>>>(coords, out);
}